// Round 6
// baseline (689.942 us; speedup 1.0000x reference)
//
#include <hip/hip_runtime.h>
#include <hip/hip_bf16.h>
#include <cstdint>

typedef __hip_bfloat16 bf16;
#define CDIV(a,b) (((a)+(b)-1)/(b))

typedef __attribute__((ext_vector_type(8))) short short8;
typedef __attribute__((ext_vector_type(8))) unsigned short usht8;
typedef __attribute__((ext_vector_type(4))) float f32x4v;

// ---------------- device helpers ----------------
__device__ __forceinline__ float lrelu02(float x) { return fmaxf(x, 0.f) + 0.2f * fminf(x, 0.f); }

__device__ __forceinline__ float toF(float x) { return x; }
__device__ __forceinline__ float toF(bf16 x) { return __bfloat162float(x); }

__device__ __forceinline__ float b2f(unsigned short u) {
    return __uint_as_float((unsigned)u << 16);
}
// f32 -> bf16 bits, round-to-nearest-even
__device__ __forceinline__ unsigned short f2b(float f) {
    unsigned u = __float_as_uint(f);
    unsigned r = u + 0x7FFFu + ((u >> 16) & 1u);
    return (unsigned short)(r >> 16);
}

// unpack 8 bf16 (4 u32) -> 8 f32
__device__ __forceinline__ void unp8(uint4 v, float* o) {
#pragma unroll
    for (int j = 0; j < 4; ++j) {
        unsigned x = (&v.x)[j];
        o[2 * j]     = __uint_as_float(x << 16);
        o[2 * j + 1] = __uint_as_float(x & 0xffff0000u);
    }
}

// swizzled LDS index (ushort units) for [row][32] tiles, 8-elem granularity
__device__ __forceinline__ int swz(int row, int kg) {
    return row * 32 + (kg ^ ((row >> 1) & 3)) * 8;
}

// ---------------- fill ----------------
__global__ void fill_i32(int* __restrict__ p, int v, long n) {
    long i = (long)blockIdx.x * blockDim.x + threadIdx.x;
    long st = (long)gridDim.x * blockDim.x;
    for (; i < n; i += st) p[i] = v;
}

// ---------------- CSR build ----------------
__global__ void hist_kernel(const int* __restrict__ ed, int* __restrict__ deg, int E) {
    int e = blockIdx.x * blockDim.x + threadIdx.x;
    if (e < E) atomicAdd(&deg[ed[e]], 1);
}

#define SCAN_T 256
#define SCAN_E 16
__global__ void __launch_bounds__(SCAN_T) scan1_kernel(
    const int* __restrict__ deg, int* __restrict__ off,
    int* __restrict__ bsum, int n)
{
    __shared__ int lds[SCAN_T];
    const int tb = blockIdx.x * (SCAN_T * SCAN_E) + threadIdx.x * SCAN_E;
    int v[SCAN_E];
    int tot = 0;
#pragma unroll
    for (int j = 0; j < SCAN_E; ++j) {
        v[j] = (tb + j < n) ? deg[tb + j] : 0;
        tot += v[j];
    }
    lds[threadIdx.x] = tot;
    __syncthreads();
    for (int s = 1; s < SCAN_T; s <<= 1) {
        int t = (threadIdx.x >= s) ? lds[threadIdx.x - s] : 0;
        __syncthreads();
        lds[threadIdx.x] += t;
        __syncthreads();
    }
    int run = (threadIdx.x > 0) ? lds[threadIdx.x - 1] : 0;
#pragma unroll
    for (int j = 0; j < SCAN_E; ++j) {
        if (tb + j < n) off[tb + j] = run;
        run += v[j];
    }
    if (threadIdx.x == SCAN_T - 1) bsum[blockIdx.x] = lds[SCAN_T - 1];
}
__global__ void scan2_kernel(int* __restrict__ bsum, int nb) {
    int t = threadIdx.x;
    int orig = (t < nb) ? bsum[t] : 0;
    int v = orig;
    for (int s = 1; s < 64; s <<= 1) {
        int u = __shfl_up(v, s);
        if (t >= s) v += u;
    }
    if (t < nb) bsum[t] = v - orig;
}
__global__ void scan3_kernel(int* __restrict__ off, const int* __restrict__ bsum, int n) {
    int i = blockIdx.x * blockDim.x + threadIdx.x;
    if (i < n) off[i] += bsum[i / (SCAN_T * SCAN_E)];
}

__global__ void csr_fill_kernel(
    const int* __restrict__ es, const int* __restrict__ ed,
    const float* __restrict__ ea, const int* __restrict__ off,
    int* __restrict__ cur, int2* __restrict__ rec, int E)
{
    int e = blockIdx.x * blockDim.x + threadIdx.x;
    if (e >= E) return;
    int d = ed[e];
    int r = atomicAdd(&cur[d], 1);
    int2 q; q.x = es[e]; q.y = __float_as_int(ea[e]);
    rec[off[d] + r] = q;
}

// ---------------- weight transpose+convert ----------------
struct TxArgs {
    const float* src[10];
    unsigned short* dst[10];
    int K[10];
    int N[10];
};
__global__ void txp_kernel(TxArgs a) {
    const int m = blockIdx.y;
    const int K = a.K[m], N = a.N[m];
    const long total = (long)K * N;
    const float* __restrict__ s = a.src[m];
    unsigned short* __restrict__ d = a.dst[m];
    for (long i = (long)blockIdx.x * blockDim.x + threadIdx.x; i < total;
         i += (long)gridDim.x * blockDim.x) {
        int k = (int)(i / N), nn = (int)(i - (long)k * N);
        d[(long)nn * K + k] = f2b(s[i]);
    }
}

// ---------------- MFMA GEMM ----------------
template<int K, int N, bool GATHER>
__global__ void __launch_bounds__(256) gemm_kernel(
    const void* __restrict__ Asrc, const int* __restrict__ ids,
    const unsigned short* __restrict__ Wt, const float* __restrict__ bias,
    unsigned short* __restrict__ Y, int n)
{
    constexpr int NCT = N / 64;
    const int t = threadIdx.x;
    const int wid = t >> 6, lane = t & 63;
    const int row0 = blockIdx.x * 64;

    __shared__ unsigned short As[64 * 32];
    __shared__ unsigned short Ws[N * 32];

    f32x4v acc[4][NCT];
#pragma unroll
    for (int rt = 0; rt < 4; ++rt)
#pragma unroll
        for (int ct = 0; ct < NCT; ++ct) acc[rt][ct] = (f32x4v){0.f, 0.f, 0.f, 0.f};

    const int r_st = t >> 2, kg_st = t & 3;
    const int grow = row0 + r_st;
    long abase = 0;
    if (grow < n) abase = GATHER ? (long)ids[grow] * K : (long)grow * K;

    for (int kt = 0; kt < K / 32; ++kt) {
        usht8 av = (usht8)0;
        if (grow < n) {
            if (GATHER) {
                const float* p = (const float*)Asrc + abase + kt * 32 + kg_st * 8;
#pragma unroll
                for (int j = 0; j < 8; ++j) av[j] = f2b(p[j]);
            } else {
                av = *(const usht8*)((const unsigned short*)Asrc + abase + kt * 32 + kg_st * 8);
            }
        }
        *(usht8*)&As[swz(r_st, kg_st)] = av;
#pragma unroll
        for (int i = 0; i < NCT; ++i) {
            int idx = t + i * 256;
            int c = idx >> 2, kg = idx & 3;
            *(usht8*)&Ws[swz(c, kg)] = *(const usht8*)&Wt[(long)c * K + kt * 32 + kg * 8];
        }
        __syncthreads();

        const int kgrp = lane >> 4;
        short8 af[4];
#pragma unroll
        for (int rt = 0; rt < 4; ++rt)
            af[rt] = *(const short8*)&As[swz(rt * 16 + (lane & 15), kgrp)];
#pragma unroll
        for (int ct = 0; ct < NCT; ++ct) {
            int col = wid * (N / 4) + ct * 16 + (lane & 15);
            short8 bfr = *(const short8*)&Ws[swz(col, kgrp)];
#pragma unroll
            for (int rt = 0; rt < 4; ++rt)
                acc[rt][ct] = __builtin_amdgcn_mfma_f32_16x16x32_bf16(af[rt], bfr, acc[rt][ct], 0, 0, 0);
        }
        __syncthreads();
    }

#pragma unroll
    for (int ct = 0; ct < NCT; ++ct) {
        int col = wid * (N / 4) + ct * 16 + (lane & 15);
        float bb = bias[col];
#pragma unroll
        for (int rt = 0; rt < 4; ++rt) {
#pragma unroll
            for (int j = 0; j < 4; ++j) {
                int row = row0 + rt * 16 + (lane >> 4) * 4 + j;
                if (row < n) Y[(long)row * N + col] = f2b(acc[rt][ct][j] + bb);
            }
        }
    }
}

// ---------------- fused GATv2 layer (4-edge subgroups) ----------------
// lane = sub*16 + h*4 + p; subgroup `sub` processes edge j0+sub;
// lane owns 16 channels c0 = h*64 + p*16 .. +15.
// Per-subgroup independent online softmax; states merged once per dst.
// Edge records read via readfirstlane-forced scalar loads (SMEM pipe).
template<bool CONCAT>
__global__ void __launch_bounds__(256) gat_fused_kernel(
    const int* __restrict__ deg, const int* __restrict__ off,
    const int2* __restrict__ rec,
    const bf16* __restrict__ xl, const bf16* __restrict__ xr,
    const float* __restrict__ We, const float* __restrict__ att,
    const float* __restrict__ bias,
    const float* __restrict__ g, const float* __restrict__ be,
    void* __restrict__ yout, int n)
{
    const int lane = threadIdx.x & 63;
    const int d = blockIdx.x * 4 + (threadIdx.x >> 6);
    if (d >= n) return;
    const int sub = lane >> 4;
    const int w   = lane & 15;
    const int h   = w >> 2;
    const int p   = w & 3;
    const int c0  = h * 64 + p * 16;

    // per-lane constants: 16 channels of We, att, xr
    float We16[16], att16[16], xr16[16];
    {
        const float4* Wp = (const float4*)(We + c0);
        const float4* Ap = (const float4*)(att + c0);
#pragma unroll
        for (int j = 0; j < 4; ++j) {
            float4 wv = Wp[j], av = Ap[j];
            We16[j*4+0] = wv.x; We16[j*4+1] = wv.y; We16[j*4+2] = wv.z; We16[j*4+3] = wv.w;
            att16[j*4+0] = av.x; att16[j*4+1] = av.y; att16[j*4+2] = av.z; att16[j*4+3] = av.w;
        }
        const uint4* xrp = (const uint4*)((const unsigned short*)xr + (long)d * 256 + c0);
        unp8(xrp[0], xr16); unp8(xrp[1], xr16 + 8);
    }

    float m = -1e30f, den = 0.f;
    float acc[16];
#pragma unroll
    for (int i = 0; i < 16; ++i) acc[i] = 0.f;

    const int dg = __builtin_amdgcn_readfirstlane(deg[d]);
    const int o0 = __builtin_amdgcn_readfirstlane(off[d]);
    const int* __restrict__ recI = (const int*)rec;
    const unsigned short* __restrict__ xlp = (const unsigned short*)xl;

    for (int j0 = 0; j0 < dg; j0 += 4) {
        const int rb = __builtin_amdgcn_readfirstlane(2 * (o0 + j0));
        int r0 = recI[rb+0], r1 = recI[rb+1], r2 = recI[rb+2], r3 = recI[rb+3];
        int r4 = recI[rb+4], r5 = recI[rb+5], r6 = recI[rb+6], r7 = recI[rb+7];

        const bool valid = (j0 + sub) < dg;
        int se  = sub < 2 ? (sub == 0 ? r0 : r2) : (sub == 2 ? r4 : r6);
        int abt = sub < 2 ? (sub == 0 ? r1 : r3) : (sub == 2 ? r5 : r7);
        se = valid ? se : 0;
        const float a = __int_as_float(abt);

        const uint4* xp = (const uint4*)(xlp + (long)se * 256 + c0);
        uint4 x0 = xp[0], x1 = xp[1];
        float xv[16];
        unp8(x0, xv); unp8(x1, xv + 8);

        float part = 0.f;
#pragma unroll
        for (int i = 0; i < 16; ++i) {
            float t = xv[i] + fmaf(a, We16[i], xr16[i]);
            part = fmaf(lrelu02(t), att16[i], part);
        }
        // reduce over the 4 lanes of (sub,h) -> head logit (quad DPP)
        part += __shfl_xor(part, 1);
        part += __shfl_xor(part, 2);
        float l = valid ? part : -1e30f;

        float mn = fmaxf(m, l);
        float sc = __expf(m - mn);
        float pe = __expf(l - mn);
        m = mn;
        den = fmaf(den, sc, pe);
#pragma unroll
        for (int i = 0; i < 16; ++i) acc[i] = fmaf(acc[i], sc, pe * xv[i]);
    }

    // ---- merge the 4 subgroup states (per head) ----
    float M = fmaxf(m, __shfl_xor(m, 16));
    M = fmaxf(M, __shfl_xor(M, 32));
    float scm = __expf(m - M);
    float dn = den * scm;
    dn += __shfl_xor(dn, 16);
    dn += __shfl_xor(dn, 32);
    const float idT = 1.f / (dn + 1e-16f);
#pragma unroll
    for (int i = 0; i < 16; ++i) {
        float t = acc[i] * scm;
        t += __shfl_xor(t, 16);
        t += __shfl_xor(t, 32);
        acc[i] = t;
    }

    if (CONCAT) {
        float bi[16], gg[16], bb[16];
        {
            const float4* Bp = (const float4*)(bias + c0);
            const float4* Gp = (const float4*)(g + c0);
            const float4* Ep = (const float4*)(be + c0);
#pragma unroll
            for (int j = 0; j < 4; ++j) {
                float4 b4 = Bp[j], g4 = Gp[j], e4 = Ep[j];
                bi[j*4+0]=b4.x; bi[j*4+1]=b4.y; bi[j*4+2]=b4.z; bi[j*4+3]=b4.w;
                gg[j*4+0]=g4.x; gg[j*4+1]=g4.y; gg[j*4+2]=g4.z; gg[j*4+3]=g4.w;
                bb[j*4+0]=e4.x; bb[j*4+1]=e4.y; bb[j*4+2]=e4.z; bb[j*4+3]=e4.w;
            }
        }
        float v[16], s1 = 0.f, s2 = 0.f;
#pragma unroll
        for (int i = 0; i < 16; ++i) {
            v[i] = fmaf(acc[i], idT, bi[i]);
            s1 += v[i]; s2 = fmaf(v[i], v[i], s2);
        }
#pragma unroll
        for (int st = 1; st < 16; st <<= 1) {
            s1 += __shfl_xor(s1, st);
            s2 += __shfl_xor(s2, st);
        }
        float mean = s1 * (1.f / 256.f);
        float var = s2 * (1.f / 256.f) - mean * mean;
        float rr = rsqrtf(var + 1e-5f);
        if (sub == 0) {
            unsigned out[8];
#pragma unroll
            for (int j = 0; j < 8; ++j) {
                float o0f = lrelu02(fmaf(gg[2*j]   * rr, v[2*j]   - mean, bb[2*j]));
                float o1f = lrelu02(fmaf(gg[2*j+1] * rr, v[2*j+1] - mean, bb[2*j+1]));
                out[j] = (unsigned)f2b(o0f) | ((unsigned)f2b(o1f) << 16);
            }
            uint4* yp = (uint4*)((unsigned short*)yout + (long)d * 256 + c0);
            yp[0] = make_uint4(out[0], out[1], out[2], out[3]);
            yp[1] = make_uint4(out[4], out[5], out[6], out[7]);
        }
    } else {
        float vh[16];
#pragma unroll
        for (int i = 0; i < 16; ++i) vh[i] = acc[i] * idT;
        // sum over heads (lanes differing in bits 2,3)
#pragma unroll
        for (int i = 0; i < 16; ++i) {
            vh[i] += __shfl_xor(vh[i], 4);
            vh[i] += __shfl_xor(vh[i], 8);
        }
        const int oc = p * 16;
        float bi[16], gg[16], bb[16];
        {
            const float4* Bp = (const float4*)(bias + oc);
            const float4* Gp = (const float4*)(g + oc);
            const float4* Ep = (const float4*)(be + oc);
#pragma unroll
            for (int j = 0; j < 4; ++j) {
                float4 b4 = Bp[j], g4 = Gp[j], e4 = Ep[j];
                bi[j*4+0]=b4.x; bi[j*4+1]=b4.y; bi[j*4+2]=b4.z; bi[j*4+3]=b4.w;
                gg[j*4+0]=g4.x; gg[j*4+1]=g4.y; gg[j*4+2]=g4.z; gg[j*4+3]=g4.w;
                bb[j*4+0]=e4.x; bb[j*4+1]=e4.y; bb[j*4+2]=e4.z; bb[j*4+3]=e4.w;
            }
        }
        float v[16], s1 = 0.f, s2 = 0.f;
#pragma unroll
        for (int i = 0; i < 16; ++i) {
            v[i] = fmaf(0.25f, vh[i], bi[i]);
            s1 += v[i]; s2 = fmaf(v[i], v[i], s2);
        }
        s1 += __shfl_xor(s1, 1); s2 += __shfl_xor(s2, 1);
        s1 += __shfl_xor(s1, 2); s2 += __shfl_xor(s2, 2);
        float mean = s1 * (1.f / 64.f);
        float var = s2 * (1.f / 64.f) - mean * mean;
        float rr = rsqrtf(var + 1e-5f);
        if (sub == 0 && h == 0) {
            float* yp = (float*)yout + (long)d * 64 + oc;
#pragma unroll
            for (int j = 0; j < 4; ++j) {
                float4 o;
                o.x = lrelu02(fmaf(gg[4*j+0] * rr, v[4*j+0] - mean, bb[4*j+0]));
                o.y = lrelu02(fmaf(gg[4*j+1] * rr, v[4*j+1] - mean, bb[4*j+1]));
                o.z = lrelu02(fmaf(gg[4*j+2] * rr, v[4*j+2] - mean, bb[4*j+2]));
                o.w = lrelu02(fmaf(gg[4*j+3] * rr, v[4*j+3] - mean, bb[4*j+3]));
                *(float4*)(yp + 4 * j) = o;
            }
        }
    }
}

// ---------------- host orchestration ----------------
extern "C" void kernel_launch(void* const* d_in, const int* in_sizes, int n_in,
                              void* d_out, int out_size, void* d_ws, size_t ws_size,
                              hipStream_t stream)
{
    auto F = [&](int i) { return (const float*)d_in[i]; };
    auto I = [&](int i) { return (const int*)d_in[i]; };

    const int NU = in_sizes[0];
    const int NM = in_sizes[1];
    const int E  = in_sizes[2] / 2;

    const int* user_ids  = I(0);
    const int* movie_ids = I(1);
    const int* ei_um = I(2);
    const int* ei_mu = I(3);
    const float* ea_um = F(4);
    const float* ea_mu = F(5);
    const float* user_emb  = F(6);
    const float* movie_emb = F(7);
    const float* W_user = F(8),  *b_user = F(9);
    const float* W_movie = F(10), *b_movie = F(11);
    const int L0UM = 12, L0MU = 19, L1UM = 26, L1MU = 33;
    const float* g0u = F(40), *be0u = F(41);
    const float* g0m = F(42), *be0m = F(43);
    const float* g1u = F(44), *be1u = F(45);
    const float* g1m = F(46), *be1m = F(47);

    // ---- workspace layout ----
    char* w = (char*)d_ws;
    size_t off = 0;
    auto alloc = [&](size_t bytes) -> void* {
        void* p = w + off;
        off = (off + bytes + 255) & ~(size_t)255;
        return p;
    };
    bf16* UB1 = (bf16*)alloc((size_t)NU * 256 * 2);
    bf16* UB2 = (bf16*)alloc((size_t)NU * 256 * 2);
    bf16* MB1 = (bf16*)alloc((size_t)NM * 256 * 2);
    bf16* MB2 = (bf16*)alloc((size_t)NM * 256 * 2);
    bf16* MB3 = (bf16*)alloc((size_t)NM * 256 * 2);
    unsigned short* xu0b = (unsigned short*)alloc((size_t)NU * 64 * 2);
    unsigned short* xm0b = (unsigned short*)alloc((size_t)NM * 64 * 2);
    int* deg_m = (int*)alloc((size_t)NM * 4);
    int* off_m = (int*)alloc((size_t)NM * 4);
    int* cur_m = (int*)alloc((size_t)NM * 4);
    int2* rec_m = (int2*)alloc((size_t)(E + 4) * 8);
    int* deg_u = (int*)alloc((size_t)NU * 4);
    int* off_u = (int*)alloc((size_t)NU * 4);
    int* cur_u = (int*)alloc((size_t)NU * 4);
    int2* rec_u = (int2*)alloc((size_t)(E + 4) * 8);
    int* bsum = (int*)alloc(64 * 4);
    unsigned short* wt_user   = (unsigned short*)alloc(64 * 64 * 2);
    unsigned short* wt_movie  = (unsigned short*)alloc(64 * 64 * 2);
    unsigned short* wt_l0um_l = (unsigned short*)alloc(64 * 256 * 2);
    unsigned short* wt_l0um_r = (unsigned short*)alloc(64 * 256 * 2);
    unsigned short* wt_l0mu_l = (unsigned short*)alloc(64 * 256 * 2);
    unsigned short* wt_l0mu_r = (unsigned short*)alloc(64 * 256 * 2);
    unsigned short* wt_l1um_l = (unsigned short*)alloc(256 * 256 * 2);
    unsigned short* wt_l1um_r = (unsigned short*)alloc(256 * 256 * 2);
    unsigned short* wt_l1mu_l = (unsigned short*)alloc(256 * 256 * 2);
    unsigned short* wt_l1mu_r = (unsigned short*)alloc(256 * 256 * 2);
    if (off > ws_size) return;

    float* out_u = (float*)d_out;
    float* out_m = out_u + (size_t)NU * 64;

    const int FB = 256;

    // ---- weight conversion ----
    TxArgs tx;
    const float* srcs[10] = {W_user, W_movie, F(L0UM+0), F(L0UM+2), F(L0MU+0), F(L0MU+2),
                             F(L1UM+0), F(L1UM+2), F(L1MU+0), F(L1MU+2)};
    unsigned short* dsts[10] = {wt_user, wt_movie, wt_l0um_l, wt_l0um_r, wt_l0mu_l, wt_l0mu_r,
                                wt_l1um_l, wt_l1um_r, wt_l1mu_l, wt_l1mu_r};
    int Ks[10] = {64, 64, 64, 64, 64, 64, 256, 256, 256, 256};
    int Ns[10] = {64, 64, 256, 256, 256, 256, 256, 256, 256, 256};
    for (int i = 0; i < 10; ++i) { tx.src[i] = srcs[i]; tx.dst[i] = dsts[i]; tx.K[i] = Ks[i]; tx.N[i] = Ns[i]; }
    txp_kernel<<<dim3(64, 10), 256, 0, stream>>>(tx);

    // ---- CSR build: um (dst = movies) ----
    fill_i32<<<CDIV(NM, FB), FB, 0, stream>>>(deg_m, 0, NM);
    hist_kernel<<<CDIV(E, FB), FB, 0, stream>>>(ei_um + E, deg_m, E);
    scan1_kernel<<<CDIV(NM, SCAN_T * SCAN_E), SCAN_T, 0, stream>>>(deg_m, off_m, bsum, NM);
    scan2_kernel<<<1, 64, 0, stream>>>(bsum, CDIV(NM, SCAN_T * SCAN_E));
    scan3_kernel<<<CDIV(NM, FB), FB, 0, stream>>>(off_m, bsum, NM);
    fill_i32<<<CDIV(NM, FB), FB, 0, stream>>>(cur_m, 0, NM);
    csr_fill_kernel<<<CDIV(E, FB), FB, 0, stream>>>(ei_um, ei_um + E, ea_um, off_m, cur_m, rec_m, E);

    // ---- CSR build: mu (dst = users) ----
    fill_i32<<<CDIV(NU, FB), FB, 0, stream>>>(deg_u, 0, NU);
    hist_kernel<<<CDIV(E, FB), FB, 0, stream>>>(ei_mu + E, deg_u, E);
    scan1_kernel<<<CDIV(NU, SCAN_T * SCAN_E), SCAN_T, 0, stream>>>(deg_u, off_u, bsum, NU);
    scan2_kernel<<<1, 64, 0, stream>>>(bsum, CDIV(NU, SCAN_T * SCAN_E));
    scan3_kernel<<<CDIV(NU, FB), FB, 0, stream>>>(off_u, bsum, NU);
    fill_i32<<<CDIV(NU, FB), FB, 0, stream>>>(cur_u, 0, NU);
    csr_fill_kernel<<<CDIV(E, FB), FB, 0, stream>>>(ei_mu, ei_mu + E, ea_mu, off_u, cur_u, rec_u, E);

    // ---- phase 0: embedding gather + input projection (MFMA) ----
    gemm_kernel<64, 64, true><<<CDIV(NU, 64), 256, 0, stream>>>(user_emb, user_ids, wt_user, b_user, xu0b, NU);
    gemm_kernel<64, 64, true><<<CDIV(NM, 64), 256, 0, stream>>>(movie_emb, movie_ids, wt_movie, b_movie, xm0b, NM);

    // ---- layer-0 projections ----
    gemm_kernel<64, 256, false><<<CDIV(NU, 64), 256, 0, stream>>>(xu0b, nullptr, wt_l0um_l, F(L0UM+1), (unsigned short*)UB1, NU); // xl_u0
    gemm_kernel<64, 256, false><<<CDIV(NM, 64), 256, 0, stream>>>(xm0b, nullptr, wt_l0um_r, F(L0UM+3), (unsigned short*)MB1, NM); // xr_m0
    gemm_kernel<64, 256, false><<<CDIV(NM, 64), 256, 0, stream>>>(xm0b, nullptr, wt_l0mu_l, F(L0MU+1), (unsigned short*)MB3, NM); // xl_m0
    gemm_kernel<64, 256, false><<<CDIV(NU, 64), 256, 0, stream>>>(xu0b, nullptr, wt_l0mu_r, F(L0MU+3), (unsigned short*)UB2, NU); // xr_u0

    // ---- layer 0 fused GAT ----
    gat_fused_kernel<true><<<CDIV(NM, 4), 256, 0, stream>>>(
        deg_m, off_m, rec_m, UB1, MB1, F(L0UM+4), F(L0UM+5), F(L0UM+6), g0m, be0m, MB2, NM);
    gat_fused_kernel<true><<<CDIV(NU, 4), 256, 0, stream>>>(
        deg_u, off_u, rec_u, MB3, UB2, F(L0MU+4), F(L0MU+5), F(L0MU+6), g0u, be0u, UB1, NU);

    // ---- layer-1 projections + fused GAT ----
    gemm_kernel<256, 256, false><<<CDIV(NU, 64), 256, 0, stream>>>((unsigned short*)UB1, nullptr, wt_l1um_l, F(L1UM+1), (unsigned short*)UB2, NU); // xl_u1
    gemm_kernel<256, 256, false><<<CDIV(NM, 64), 256, 0, stream>>>((unsigned short*)MB2, nullptr, wt_l1um_r, F(L1UM+3), (unsigned short*)MB1, NM); // xr_m1
    gat_fused_kernel<false><<<CDIV(NM, 4), 256, 0, stream>>>(
        deg_m, off_m, rec_m, UB2, MB1, F(L1UM+4), F(L1UM+5), F(L1UM+6), g1m, be1m, out_m, NM);

    gemm_kernel<256, 256, false><<<CDIV(NM, 64), 256, 0, stream>>>((unsigned short*)MB2, nullptr, wt_l1mu_l, F(L1MU+1), (unsigned short*)MB3, NM); // xl_m1
    gemm_kernel<256, 256, false><<<CDIV(NU, 64), 256, 0, stream>>>((unsigned short*)UB1, nullptr, wt_l1mu_r, F(L1MU+3), (unsigned short*)UB2, NU); // xr_u1
    gat_fused_kernel<false><<<CDIV(NU, 4), 256, 0, stream>>>(
        deg_u, off_u, rec_u, MB3, UB2, F(L1MU+4), F(L1MU+5), F(L1MU+6), g1u, be1u, out_u, NU);
}